// Round 1
// baseline (100.639 us; speedup 1.0000x reference)
//
#include <hip/hip_runtime.h>

typedef __attribute__((ext_vector_type(4))) int   int4v;
typedef __attribute__((ext_vector_type(4))) float float4v;

// XOR swizzle of the 16B slot index within a 64B row: spreads the
// stride-64B per-lane ds_read_b128 fragment reads across banks (<=2-way).
__device__ __forceinline__ int swz(int row, int slot) {
    return slot ^ ((row ^ (row >> 2)) & 3);
}

// Exact replica of the reference fake-quant grid index:
// scale = (up-lo)/15 (fp32); q = rint((clamp(x,lo,up)-lo)/scale), IEEE div,
// round-half-even == jnp.round. q is guaranteed in [0,15].
__device__ __forceinline__ int quant1(float x, float lo, float up, float scale) {
    float xc = fminf(fmaxf(x, lo), up);
    return (int)rintf((xc - lo) / scale);
}

__global__ __launch_bounds__(256, 4) void qmm_i8_kernel(
    const float* __restrict__ A, const float* __restrict__ B,
    const float* __restrict__ aLo, const float* __restrict__ aUp,
    const float* __restrict__ bLo, const float* __restrict__ bUp,
    float* __restrict__ Out)
{
    // qA: [row 0..255][k 0..63] i8, stored as int (4 bytes = 4 consecutive k)
    // qB: B transposed -> [col 0..255][k 0..63] i8 (both operands K-contiguous)
    __shared__ int   qA[256 * 16];
    __shared__ int   qB[256 * 16];
    __shared__ float RAf[256];   // sA*lB*rowsum(qA[i]) + 32*lA*lB
    __shared__ float CBf[256];   // lA*sB*colsum(qB[j]) + 32*lA*lB

    const int tid = threadIdx.x;
    const int b   = blockIdx.x;

    const float lA = aLo[0], uA = aUp[0];
    const float lB = bLo[0], uB = bUp[0];
    const float sA  = (uA - lA) / 15.0f;
    const float sB  = (uB - lB) / 15.0f;
    const float sAB = sA * sB;

    const float4v* A4 = (const float4v*)(A + (size_t)b * 256 * 64);
    const float4v* B4 = (const float4v*)(B + (size_t)b * 64 * 256);
    float* outb = Out + (size_t)b * 256 * 256;

    // ---- stage A: coalesced float4 loads, quantize, pack 4 x i8 -> int ----
    #pragma unroll
    for (int it = 0; it < 16; ++it) {
        int f = it * 256 + tid;            // float4 index 0..4095
        float4v v = A4[f];
        int q0 = quant1(v[0], lA, uA, sA);
        int q1 = quant1(v[1], lA, uA, sA);
        int q2 = quant1(v[2], lA, uA, sA);
        int q3 = quant1(v[3], lA, uA, sA);
        int p  = q0 | (q1 << 8) | (q2 << 16) | (q3 << 24);
        int row = f >> 4, chunk = f & 15;  // row 0..255, 16 ints per row
        qA[row * 16 + swz(row, chunk >> 2) * 4 + (chunk & 3)] = p;
    }

    // ---- stage B: coalesced loads of 4x4 fp32 tile, transpose in regs ----
    const int u  = tid & 63;   // column group: cols 4u..4u+3
    const int kg = tid >> 6;   // wave id -> 4-byte offset inside 16B k-slot
    #pragma unroll
    for (int kb = 0; kb < 4; ++kb) {
        int k0 = kb * 16 + kg * 4;         // k rows k0..k0+3
        int q[4][4];
        #pragma unroll
        for (int r = 0; r < 4; ++r) {
            float4v v = B4[(size_t)(k0 + r) * 64 + u];   // fully coalesced
            q[r][0] = quant1(v[0], lB, uB, sB);
            q[r][1] = quant1(v[1], lB, uB, sB);
            q[r][2] = quant1(v[2], lB, uB, sB);
            q[r][3] = quant1(v[3], lB, uB, sB);
        }
        #pragma unroll
        for (int c = 0; c < 4; ++c) {
            int col = u * 4 + c;
            int p = q[0][c] | (q[1][c] << 8) | (q[2][c] << 16) | (q[3][c] << 24);
            qB[col * 16 + swz(col, kb) * 4 + kg] = p;
        }
    }

    __syncthreads();

    // ---- row sums of qA / col sums of B (rows of qB), byte-sum trick ----
    {
        unsigned sa = 0, sb = 0;
        #pragma unroll
        for (int j = 0; j < 16; ++j) {
            unsigned pa = (unsigned)qA[tid * 16 + swz(tid, j >> 2) * 4 + (j & 3)];
            unsigned pb = (unsigned)qB[tid * 16 + swz(tid, j >> 2) * 4 + (j & 3)];
            sa += (pa * 0x01010101u) >> 24;   // bytes <= 15, no carry
            sb += (pb * 0x01010101u) >> 24;
        }
        float c32 = 32.0f * lA * lB;
        RAf[tid] = sA * lB * (float)sa + c32;
        CBf[tid] = lA * sB * (float)sb + c32;
    }
    __syncthreads();

    // ---- compute: each wave owns 64 rows x all 256 cols, 16x16x64 MFMA ----
    const int wave = tid >> 6, lane = tid & 63;
    const int lr = lane & 15;   // fragment row (A) / col (B) / out col
    const int lk = lane >> 4;   // k-block 0..3 (16 i8 each)

    int4v afrag[4];
    #pragma unroll
    for (int rt = 0; rt < 4; ++rt) {
        int row = wave * 64 + rt * 16 + lr;
        afrag[rt] = *(const int4v*)&qA[row * 16 + swz(row, lk) * 4];
    }

    #pragma unroll 4
    for (int ct = 0; ct < 16; ++ct) {
        int col = ct * 16 + lr;
        int4v bfrag = *(const int4v*)&qB[col * 16 + swz(col, lk) * 4];
        float cb = CBf[col];               // out col == lane&15 == lr
        #pragma unroll
        for (int rt = 0; rt < 4; ++rt) {
            int4v acc = {0, 0, 0, 0};
            acc = __builtin_amdgcn_mfma_i32_16x16x64_i8(afrag[rt], bfrag, acc, 0, 0, 0);
            int orow = wave * 64 + rt * 16 + lk * 4;   // C/D: row=(lane>>4)*4+reg
            #pragma unroll
            for (int r = 0; r < 4; ++r) {
                outb[(size_t)(orow + r) * 256 + col] =
                    sAB * (float)acc[r] + RAf[orow + r] + cb;
            }
        }
    }
}

extern "C" void kernel_launch(void* const* d_in, const int* in_sizes, int n_in,
                              void* d_out, int out_size, void* d_ws, size_t ws_size,
                              hipStream_t stream) {
    const float* A   = (const float*)d_in[0];
    const float* B   = (const float*)d_in[1];
    const float* aLo = (const float*)d_in[2];
    const float* aUp = (const float*)d_in[3];
    const float* bLo = (const float*)d_in[4];
    const float* bUp = (const float*)d_in[5];
    float* Out = (float*)d_out;

    int batches = in_sizes[0] / (256 * 64);   // 128*8 = 1024
    qmm_i8_kernel<<<batches, 256, 0, stream>>>(A, B, aLo, aUp, bLo, bUp, Out);
}